// Round 25
// baseline (567.022 us; speedup 1.0000x reference)
//
#include <hip/hip_runtime.h>
#include <math.h>

#define N_PTS 8192
#define ICP_STEPS 21      // STEPLIM + 1 scan iterations
#define ICP_TOL 1e-4

#define NBLK 256          // 4 tiers x 64 blocks; CP dispatches in bid order
#define BSIZE 512         // 8 waves
#define CH 4096           // candidates per LDS chunk (64 KiB)
#define NCH 2             // 2 * 4096 = 8192
#define NSETS 16          // accumulator sets

struct IcpCtl {
  double err;
  double Rc[9];     // cumulative rotation (row-major): pc = Rc*p1 + tc
  double tc[3];
  int done;
};

// ---------------------------------------------------------------------------
// prep: p2aug = (x,y,z,|b|^2); acc/tickets zeroed; ctl reset (every replay)
// ---------------------------------------------------------------------------
__global__ __launch_bounds__(256) void icp_prep(const float* __restrict__ p2,
                                                float4* __restrict__ p2aug,
                                                IcpCtl* __restrict__ ctl,
                                                double* __restrict__ acc,
                                                unsigned* __restrict__ gtick,
                                                unsigned* __restrict__ root) {
  int t = blockIdx.x * 256 + threadIdx.x;   // grid covers exactly N_PTS
  float x = p2[3*t], y = p2[3*t+1], z = p2[3*t+2];
  p2aug[t] = make_float4(x, y, z, fmaf(x, x, fmaf(y, y, z*z)));
  if (t < NSETS * 16) acc[t] = 0.0;
  if (t < NSETS) gtick[t << 4] = 0u;
  if (t == 0) {
    *root = 0u;
    ctl->err = 0.0; ctl->done = 0;
    #pragma unroll
    for (int i = 0; i < 9; ++i) ctl->Rc[i] = (i % 4 == 0) ? 1.0 : 0.0;
    ctl->tc[0] = ctl->tc[1] = ctl->tc[2] = 0.0;
  }
}

// ---------------------------------------------------------------------------
// Register-only 3x3 Kabsch from raw sums (no runtime-indexed reg arrays).
// ---------------------------------------------------------------------------
__device__ __forceinline__ void kabsch_solve(const double* s, double* R, double* T) {
  const double n = (double)N_PTS;
  const double c1x = s[1]/n, c1y = s[2]/n, c1z = s[3]/n;
  const double c2x = s[4]/n, c2y = s[5]/n, c2z = s[6]/n;
  const double h00 = s[7]  - n*c1x*c2x, h01 = s[8]  - n*c1x*c2y, h02 = s[9]  - n*c1x*c2z;
  const double h10 = s[10] - n*c1y*c2x, h11 = s[11] - n*c1y*c2y, h12 = s[12] - n*c1y*c2z;
  const double h20 = s[13] - n*c1z*c2x, h21 = s[14] - n*c1z*c2y, h22 = s[15] - n*c1z*c2z;

  double a00 = h00*h00 + h10*h10 + h20*h20;
  double a01 = h00*h01 + h10*h11 + h20*h21;
  double a02 = h00*h02 + h10*h12 + h20*h22;
  double a11 = h01*h01 + h11*h11 + h21*h21;
  double a12 = h01*h02 + h11*h12 + h21*h22;
  double a22 = h02*h02 + h12*h12 + h22*h22;

  double v00=1.0, v01=0.0, v02=0.0;
  double v10=0.0, v11=1.0, v12=0.0;
  double v20=0.0, v21=0.0, v22=1.0;

#define ROT3(app, aqq, apq, arp, arq, vpa, vqa, vpb, vqb, vpc, vqc)              \
  {                                                                              \
    double apq_ = apq;                                                           \
    if (fabs(apq_) > 1e-300) {                                                   \
      double tau = (aqq - app) / (2.0 * apq_);                                   \
      double tt  = (tau >= 0.0 ? 1.0 : -1.0) / (fabs(tau) + sqrt(1.0 + tau*tau));\
      double c_  = 1.0 / sqrt(1.0 + tt*tt), sn = tt * c_;                        \
      app -= tt * apq_;  aqq += tt * apq_;  apq = 0.0;                           \
      double t1 = arp, t2 = arq;                                                 \
      arp = c_*t1 - sn*t2;  arq = sn*t1 + c_*t2;                                 \
      t1 = vpa; t2 = vqa; vpa = c_*t1 - sn*t2; vqa = sn*t1 + c_*t2;              \
      t1 = vpb; t2 = vqb; vpb = c_*t1 - sn*t2; vqb = sn*t1 + c_*t2;              \
      t1 = vpc; t2 = vqc; vpc = c_*t1 - sn*t2; vqc = sn*t1 + c_*t2;              \
    }                                                                            \
  }

  #pragma unroll
  for (int sweep = 0; sweep < 6; ++sweep) {
    ROT3(a00, a11, a01, a02, a12, v00, v01, v10, v11, v20, v21);  // (0,1)
    ROT3(a00, a22, a02, a01, a12, v00, v02, v10, v12, v20, v22);  // (0,2)
    ROT3(a11, a22, a12, a01, a02, v01, v02, v11, v12, v21, v22);  // (1,2)
  }
#undef ROT3

  double l0 = a00, l1 = a11, l2 = a22;
  double e0x=v00, e0y=v10, e0z=v20;
  double e1x=v01, e1y=v11, e1z=v21;
  double e2x=v02, e2y=v12, e2z=v22;
#define CSWAP(la, lb, xa, ya, za, xb, yb, zb)                                    \
  if (lb > la) { double t_;                                                      \
    t_ = la; la = lb; lb = t_;  t_ = xa; xa = xb; xb = t_;                       \
    t_ = ya; ya = yb; yb = t_;  t_ = za; za = zb; zb = t_; }
  CSWAP(l0, l1, e0x, e0y, e0z, e1x, e1y, e1z);
  CSWAP(l0, l2, e0x, e0y, e0z, e2x, e2y, e2z);
  CSWAP(l1, l2, e1x, e1y, e1z, e2x, e2y, e2z);
#undef CSWAP

  double detV = e0x*(e1y*e2z - e1z*e2y) - e0y*(e1x*e2z - e1z*e2x)
              + e0z*(e1x*e2y - e1y*e2x);
  const double dsg = (detV >= 0.0) ? 1.0 : -1.0;

  double u0x = h00*e0x + h01*e0y + h02*e0z;
  double u0y = h10*e0x + h11*e0y + h12*e0z;
  double u0z = h20*e0x + h21*e0y + h22*e0z;
  double n0 = sqrt(u0x*u0x + u0y*u0y + u0z*u0z);
  if (!(n0 > 1e-150)) {
    R[0]=1.0; R[1]=0.0; R[2]=0.0; R[3]=0.0; R[4]=1.0; R[5]=0.0;
    R[6]=0.0; R[7]=0.0; R[8]=1.0;
    T[0]=c2x-c1x; T[1]=c2y-c1y; T[2]=c2z-c1z;
    return;
  }
  u0x /= n0; u0y /= n0; u0z /= n0;
  double u1x = h00*e1x + h01*e1y + h02*e1z;
  double u1y = h10*e1x + h11*e1y + h12*e1z;
  double u1z = h20*e1x + h21*e1y + h22*e1z;
  const double d10 = u1x*u0x + u1y*u0y + u1z*u0z;
  u1x -= d10*u0x; u1y -= d10*u0y; u1z -= d10*u0z;
  double n1 = sqrt(u1x*u1x + u1y*u1y + u1z*u1z);
  if (!(n1 > 1e-150)) {
    R[0]=1.0; R[1]=0.0; R[2]=0.0; R[3]=0.0; R[4]=1.0; R[5]=0.0;
    R[6]=0.0; R[7]=0.0; R[8]=1.0;
    T[0]=c2x-c1x; T[1]=c2y-c1y; T[2]=c2z-c1z;
    return;
  }
  u1x /= n1; u1y /= n1; u1z /= n1;
  const double u2x = u0y*u1z - u0z*u1y;
  const double u2y = u0z*u1x - u0x*u1z;
  const double u2z = u0x*u1y - u0y*u1x;

  R[0] = e0x*u0x + e1x*u1x + dsg*e2x*u2x;
  R[1] = e0x*u0y + e1x*u1y + dsg*e2x*u2y;
  R[2] = e0x*u0z + e1x*u1z + dsg*e2x*u2z;
  R[3] = e0y*u0x + e1y*u1x + dsg*e2y*u2x;
  R[4] = e0y*u0y + e1y*u1y + dsg*e2y*u2y;
  R[5] = e0y*u0z + e1y*u1z + dsg*e2y*u2z;
  R[6] = e0z*u0x + e1z*u1x + dsg*e2z*u2x;
  R[7] = e0z*u0y + e1z*u1y + dsg*e2z*u2y;
  R[8] = e0z*u0z + e1z*u1z + dsg*e2z*u2z;
  T[0] = c2x - (R[0]*c1x + R[1]*c1y + R[2]*c1z);
  T[1] = c2y - (R[3]*c1x + R[4]*c1y + R[5]*c1z);
  T[2] = c2z - (R[6]*c1x + R[7]*c1y + R[8]*c1z);
}

// ---------------------------------------------------------------------------
// Templated per-block body: QW = queries per wave (compile-time -> all
// register arrays statically indexed). Block handles 8*QW queries starting
// at qbBlock. Scan/argmin/tail identical to R22 (partition-invariant).
// ---------------------------------------------------------------------------
template<int QW>
__device__ __forceinline__ void icp_body(
    const float* __restrict__ p1, const float4* __restrict__ p2aug,
    IcpCtl* __restrict__ ctl, double* __restrict__ acc,
    unsigned* __restrict__ gtick, unsigned* __restrict__ root,
    float* __restrict__ out,
    float4* cand, unsigned long long (*pkbuf)[7], float4* qlds,
    double (*pairbuf)[17], double (*setbuf)[17], double* totbuf,
    int* solverFlag, const int qbBlock) {
  const int tid  = threadIdx.x;
  const int lane = tid & 63;
  const int w    = tid >> 6;                // wave 0..7
  const int bid  = blockIdx.x;

  const double R0 = ctl->Rc[0], R1 = ctl->Rc[1], R2 = ctl->Rc[2];
  const double R3 = ctl->Rc[3], R4 = ctl->Rc[4], R5 = ctl->Rc[5];
  const double R6 = ctl->Rc[6], R7 = ctl->Rc[7], R8 = ctl->Rc[8];
  const double T0 = ctl->tc[0], T1 = ctl->tc[1], T2 = ctl->tc[2];

  // ---- wave w owns queries qb..qb+QW-1 end-to-end ----
  const int qb = qbBlock + w * QW;
  float axv[QW], ayv[QW], azv[QW], best[QW];
  int bidx[QW];
  #pragma unroll
  for (int j = 0; j < QW; ++j) {
    const int q = qb + j;
    const double X = (double)p1[3*q], Y = (double)p1[3*q+1], Z = (double)p1[3*q+2];
    const float qx = (float)(R0*X + R1*Y + R2*Z + T0);  // fp32-rounded (ref pc)
    const float qy = (float)(R3*X + R4*Y + R5*Z + T1);
    const float qz = (float)(R6*X + R7*Y + R8*Z + T2);
    axv[j] = -2.f*qx; ayv[j] = -2.f*qy; azv[j] = -2.f*qz;
    best[j] = __builtin_inff(); bidx[j] = 0;
    if (lane == 0) qlds[w * QW + j] = make_float4(qx, qy, qz, 0.f);
  }

  // ---- scan all candidates: 2 chunks of 4096, direct global->LDS ----
  for (int cb = 0; cb < NCH; ++cb) {
    const int cbase = cb << 12;
    #pragma unroll
    for (int kk = 0; kk < 8; ++kk)
      cand[(kk << 9) + tid] = p2aug[cbase + (kk << 9) + tid];
    __syncthreads();
    #pragma unroll 4
    for (int kk = 0; kk < 64; ++kk) {
      const int cidx = cbase + (kk << 6) + lane;
      float4 c = cand[(kk << 6) + lane];    // ds_read_b128, conflict-free
      #pragma unroll
      for (int j = 0; j < QW; ++j) {
        float d = fmaf(axv[j], c.x, fmaf(ayv[j], c.y, fmaf(azv[j], c.z, c.w)));
        if (d < best[j]) { best[j] = d; bidx[j] = cidx; }
      }
    }
    __syncthreads();
  }

  // ---- wave-local FINAL argmin: packed u64 butterfly (jnp tie order) ----
  unsigned long long pk[QW];
  #pragma unroll
  for (int j = 0; j < QW; ++j) {
    unsigned u = __float_as_uint(best[j]);
    u ^= (unsigned)((int)u >> 31) | 0x80000000u;   // monotone float->uint
    pk[j] = ((unsigned long long)u << 32) | (unsigned)bidx[j];
  }
  #pragma unroll
  for (int j = 0; j < QW; ++j) {
    #pragma unroll
    for (int o = 1; o < 64; o <<= 1) {
      unsigned long long other = __shfl_xor(pk[j], o, 64);
      pk[j] = (other < pk[j]) ? other : pk[j];
    }
  }
  if (lane == 0) {
    #pragma unroll
    for (int j = 0; j < QW; ++j) pkbuf[w][j] = pk[j];
  }
  __syncthreads();

  // ---- pair sums: tid < 8*QW handles one query (LDS-indexed, static) ----
  if (tid < 8 * QW) {
    const unsigned long long m = pkbuf[tid / QW][tid % QW];  // QW constexpr
    const unsigned idx = (unsigned)(m & 0xffffffffull);
    const float4 q4 = qlds[tid];
    const float4 b4 = p2aug[idx];           // L2-resident gather
    const double ax = q4.x, ay = q4.y, az = q4.z;
    const double bx = b4.x, by = b4.y, bz = b4.z;
    const double d2 = (ax*ax + ay*ay + az*az) + (bx*bx + by*by + bz*bz)
                    - 2.0*(ax*bx + ay*by + az*bz);
    pairbuf[tid][0]  = sqrt(fmax(d2, 1e-12));
    pairbuf[tid][1]  = ax;    pairbuf[tid][2]  = ay;    pairbuf[tid][3]  = az;
    pairbuf[tid][4]  = bx;    pairbuf[tid][5]  = by;    pairbuf[tid][6]  = bz;
    pairbuf[tid][7]  = ax*bx; pairbuf[tid][8]  = ax*by; pairbuf[tid][9]  = ax*bz;
    pairbuf[tid][10] = ay*bx; pairbuf[tid][11] = ay*by; pairbuf[tid][12] = ay*bz;
    pairbuf[tid][13] = az*bx; pairbuf[tid][14] = az*by; pairbuf[tid][15] = az*bz;
  }
  __syncthreads();

  // ---- 16 col sums -> atomicAdd into set (bid&15): <=16-way contention ----
  if (tid < 16) {
    double ssum = 0.0;
    #pragma unroll
    for (int i = 0; i < 8 * QW; ++i) ssum += pairbuf[i][tid];
    atomicAdd(acc + ((bid & 15) << 4) + tid, ssum);
  }
  // ticket tree (wave 0 issued the adds; vmcnt orders adds before tickets)
  if (tid == 0) {
    asm volatile("s_waitcnt vmcnt(0)" ::: "memory");
    const int gi = bid & 15;
    unsigned og = atomicAdd(gtick + (gi << 4), 1u);     // 16-way
    if (og == 15u) {                                    // last of group
      unsigned orr = atomicAdd(root, 1u);               // 16-way
      if (orr == 15u) *solverFlag = 1;                  // last overall
    }
  }
  __syncthreads();
  if (!*solverFlag) return;

  // ================= solver path (root-last block only) =================
  double val = 0.0;
  if (tid < 256) val = atomicAdd(acc + tid, 0.0);   // RMW-read 32 lines
  if (tid < 256) setbuf[tid >> 4][tid & 15] = val;
  __syncthreads();
  if (tid < 16) {
    double t2 = 0.0;
    #pragma unroll
    for (int i = 0; i < 16; ++i) t2 += setbuf[i][tid];
    totbuf[tid] = t2;
  }
  __syncthreads();

  if (tid == 0) {
    double sm[16];
    #pragma unroll
    for (int i = 0; i < 16; ++i) sm[i] = totbuf[i];
    double R[9], T[3];
    kabsch_solve(sm, R, T);
    // compose: pc_new = R*(Rc*p1 + tc) + T = (R*Rc)*p1 + (R*tc + T)
    double Rc[9] = {R0,R1,R2,R3,R4,R5,R6,R7,R8};
    double tc[3] = {T0,T1,T2};
    double Rn[9], tn[3];
    #pragma unroll
    for (int i = 0; i < 3; ++i) {
      #pragma unroll
      for (int j = 0; j < 3; ++j)
        Rn[3*i+j] = R[3*i+0]*Rc[0+j] + R[3*i+1]*Rc[3+j] + R[3*i+2]*Rc[6+j];
      tn[i] = R[3*i+0]*tc[0] + R[3*i+1]*tc[1] + R[3*i+2]*tc[2] + T[i];
    }
    #pragma unroll
    for (int i = 0; i < 9; ++i) ctl->Rc[i] = Rn[i];
    #pragma unroll
    for (int i = 0; i < 3; ++i) ctl->tc[i] = tn[i];
    const double errnew = sm[0];            // B == 1
    ctl->done = (fabs(ctl->err - errnew) < ICP_TOL) ? 1 : 0;
    ctl->err  = errnew;
    // out = [Rc | tc] 3x4 (kabsch(p1, Rc*p1+tc) == (Rc,tc) exactly).
    #pragma unroll
    for (int i = 0; i < 3; ++i) {
      out[4*i + 0] = (float)Rn[3*i + 0];
      out[4*i + 1] = (float)Rn[3*i + 1];
      out[4*i + 2] = (float)Rn[3*i + 2];
      out[4*i + 3] = (float)tn[i];
    }
    *root = 0u;                             // reset root ticket
  }
  // reset acc + group tickets (plain stores; boundary release publishes)
  if (tid < 256) acc[tid] = 0.0;
  if (tid < 16) gtick[tid << 4] = 0u;
}

// ---------------------------------------------------------------------------
// One FUSED ICP iteration per dispatch. R22 structure with WORK TAPERED by
// dispatch order: 4 tiers of 64 blocks get {48,40,24,16} queries each
// (Sigma = 8192). Early-dispatched blocks (more work) start during the CP
// stagger window; late blocks (less work) finish quickly -> all blocks end
// near the stagger horizon instead of stagger + full block time.
// ---------------------------------------------------------------------------
__global__ __launch_bounds__(BSIZE) void icp_step(const float* __restrict__ p1,
                                                  const float4* __restrict__ p2aug,
                                                  IcpCtl* __restrict__ ctl,
                                                  double* __restrict__ acc,
                                                  unsigned* __restrict__ gtick,
                                                  unsigned* __restrict__ root,
                                                  float* __restrict__ out) {
  if (ctl->done) return;                    // uniform across grid
  __shared__ float4 cand[CH];               // 64 KiB
  __shared__ unsigned long long pkbuf[8][7];// wave x up-to-6 queries (+pad)
  __shared__ float4 qlds[48];
  __shared__ double pairbuf[48][17];        // +1 pad
  __shared__ double setbuf[16][17];
  __shared__ double totbuf[16];
  __shared__ int solverFlag;

  if (threadIdx.x == 0) solverFlag = 0;
  // (solverFlag is read after a __syncthreads inside icp_body)

  const int bid  = blockIdx.x;
  const int tier = bid >> 6;                // 0..3 (dispatch order)
  const int lb   = bid & 63;

  switch (tier) {
    case 0: icp_body<6>(p1, p2aug, ctl, acc, gtick, root, out, cand, pkbuf,
                        qlds, pairbuf, setbuf, totbuf, &solverFlag,
                        0    + lb * 48); break;
    case 1: icp_body<5>(p1, p2aug, ctl, acc, gtick, root, out, cand, pkbuf,
                        qlds, pairbuf, setbuf, totbuf, &solverFlag,
                        3072 + lb * 40); break;
    case 2: icp_body<3>(p1, p2aug, ctl, acc, gtick, root, out, cand, pkbuf,
                        qlds, pairbuf, setbuf, totbuf, &solverFlag,
                        5632 + lb * 24); break;
    default: icp_body<2>(p1, p2aug, ctl, acc, gtick, root, out, cand, pkbuf,
                        qlds, pairbuf, setbuf, totbuf, &solverFlag,
                        7168 + lb * 16); break;
  }
}

// ---------------------------------------------------------------------------
extern "C" void kernel_launch(void* const* d_in, const int* in_sizes, int n_in,
                              void* d_out, int out_size, void* d_ws, size_t ws_size,
                              hipStream_t stream) {
  const float* p1 = (const float*)d_in[0];
  const float* p2 = (const float*)d_in[1];
  float* out = (float*)d_out;

  char* ws = (char*)d_ws;
  float4* p2aug  = (float4*)ws;                        // 128 KiB
  IcpCtl* ctl    = (IcpCtl*)(ws + 128*1024);           // ~112 B
  double* acc    = (double*)(ws + 132*1024);           // 2 KiB (16 sets x 16)
  unsigned* gtick = (unsigned*)(ws + 136*1024);        // padded tickets
  unsigned* root  = (unsigned*)(ws + 140*1024);        // 1 line

  icp_prep<<<N_PTS/256, 256, 0, stream>>>(p2, p2aug, ctl, acc, gtick, root);
  for (int it = 0; it < ICP_STEPS; ++it)
    icp_step<<<NBLK, BSIZE, 0, stream>>>(p1, p2aug, ctl, acc, gtick, root, out);
}

// Round 26
// 477.032 us; speedup vs baseline: 1.1886x; 1.1886x over previous
//
#include <hip/hip_runtime.h>
#include <math.h>

#define N_PTS 8192
#define ICP_STEPS 21      // STEPLIM + 1 scan iterations
#define ICP_TOL 1e-4

#define NBLK 256          // blocks (2 per CU at 512 thr / ~71 KB LDS)
#define BSIZE 512         // 8 waves
#define QPW 4             // queries per wave (wave owns them end-to-end)
#define CH 4096           // candidates per LDS chunk (64 KiB)
#define NCH 2             // 2 * 4096 = 8192
#define NSETS 16          // accumulator sets: contention <= 16-way

struct IcpCtl {
  double err;
  double Rc[9];     // cumulative rotation (row-major): pc = Rc*p1 + tc
  double tc[3];
  int done;
};

// ---------------------------------------------------------------------------
// prep: p2aug = (x,y,z,|b|^2); acc/tickets zeroed; ctl reset (every replay)
// ---------------------------------------------------------------------------
__global__ __launch_bounds__(256) void icp_prep(const float* __restrict__ p2,
                                                float4* __restrict__ p2aug,
                                                IcpCtl* __restrict__ ctl,
                                                double* __restrict__ acc,
                                                unsigned* __restrict__ gtick,
                                                unsigned* __restrict__ root) {
  int t = blockIdx.x * 256 + threadIdx.x;   // grid covers exactly N_PTS
  float x = p2[3*t], y = p2[3*t+1], z = p2[3*t+2];
  p2aug[t] = make_float4(x, y, z, fmaf(x, x, fmaf(y, y, z*z)));
  if (t < NSETS * 16) acc[t] = 0.0;
  if (t < NSETS) gtick[t << 4] = 0u;        // 16 tickets on separate lines
  if (t == 0) {
    *root = 0u;
    ctl->err = 0.0; ctl->done = 0;
    #pragma unroll
    for (int i = 0; i < 9; ++i) ctl->Rc[i] = (i % 4 == 0) ? 1.0 : 0.0;
    ctl->tc[0] = ctl->tc[1] = ctl->tc[2] = 0.0;
  }
}

// ---------------------------------------------------------------------------
// Register-only 3x3 Kabsch from raw sums (no runtime-indexed reg arrays).
// s[0]=sum dmin, s[1..3]=sum src, s[4..6]=sum dst, s[7..15]=sum src_i*dst_j.
// R = V diag(1,1,detV) U~^T (right-handed U~) == reference's sign-fixed SVD.
// ---------------------------------------------------------------------------
__device__ __forceinline__ void kabsch_solve(const double* s, double* R, double* T) {
  const double n = (double)N_PTS;
  const double c1x = s[1]/n, c1y = s[2]/n, c1z = s[3]/n;
  const double c2x = s[4]/n, c2y = s[5]/n, c2z = s[6]/n;
  const double h00 = s[7]  - n*c1x*c2x, h01 = s[8]  - n*c1x*c2y, h02 = s[9]  - n*c1x*c2z;
  const double h10 = s[10] - n*c1y*c2x, h11 = s[11] - n*c1y*c2y, h12 = s[12] - n*c1y*c2z;
  const double h20 = s[13] - n*c1z*c2x, h21 = s[14] - n*c1z*c2y, h22 = s[15] - n*c1z*c2z;

  double a00 = h00*h00 + h10*h10 + h20*h20;
  double a01 = h00*h01 + h10*h11 + h20*h21;
  double a02 = h00*h02 + h10*h12 + h20*h22;
  double a11 = h01*h01 + h11*h11 + h21*h21;
  double a12 = h01*h02 + h11*h12 + h21*h22;
  double a22 = h02*h02 + h12*h12 + h22*h22;

  double v00=1.0, v01=0.0, v02=0.0;
  double v10=0.0, v11=1.0, v12=0.0;
  double v20=0.0, v21=0.0, v22=1.0;

#define ROT3(app, aqq, apq, arp, arq, vpa, vqa, vpb, vqb, vpc, vqc)              \
  {                                                                              \
    double apq_ = apq;                                                           \
    if (fabs(apq_) > 1e-300) {                                                   \
      double tau = (aqq - app) / (2.0 * apq_);                                   \
      double tt  = (tau >= 0.0 ? 1.0 : -1.0) / (fabs(tau) + sqrt(1.0 + tau*tau));\
      double c_  = 1.0 / sqrt(1.0 + tt*tt), sn = tt * c_;                        \
      app -= tt * apq_;  aqq += tt * apq_;  apq = 0.0;                           \
      double t1 = arp, t2 = arq;                                                 \
      arp = c_*t1 - sn*t2;  arq = sn*t1 + c_*t2;                                 \
      t1 = vpa; t2 = vqa; vpa = c_*t1 - sn*t2; vqa = sn*t1 + c_*t2;              \
      t1 = vpb; t2 = vqb; vpb = c_*t1 - sn*t2; vqb = sn*t1 + c_*t2;              \
      t1 = vpc; t2 = vqc; vpc = c_*t1 - sn*t2; vqc = sn*t1 + c_*t2;              \
    }                                                                            \
  }

  #pragma unroll
  for (int sweep = 0; sweep < 6; ++sweep) {
    ROT3(a00, a11, a01, a02, a12, v00, v01, v10, v11, v20, v21);  // (0,1)
    ROT3(a00, a22, a02, a01, a12, v00, v02, v10, v12, v20, v22);  // (0,2)
    ROT3(a11, a22, a12, a01, a02, v01, v02, v11, v12, v21, v22);  // (1,2)
  }
#undef ROT3

  double l0 = a00, l1 = a11, l2 = a22;
  double e0x=v00, e0y=v10, e0z=v20;
  double e1x=v01, e1y=v11, e1z=v21;
  double e2x=v02, e2y=v12, e2z=v22;
#define CSWAP(la, lb, xa, ya, za, xb, yb, zb)                                    \
  if (lb > la) { double t_;                                                      \
    t_ = la; la = lb; lb = t_;  t_ = xa; xa = xb; xb = t_;                       \
    t_ = ya; ya = yb; yb = t_;  t_ = za; za = zb; zb = t_; }
  CSWAP(l0, l1, e0x, e0y, e0z, e1x, e1y, e1z);
  CSWAP(l0, l2, e0x, e0y, e0z, e2x, e2y, e2z);
  CSWAP(l1, l2, e1x, e1y, e1z, e2x, e2y, e2z);
#undef CSWAP

  double detV = e0x*(e1y*e2z - e1z*e2y) - e0y*(e1x*e2z - e1z*e2x)
              + e0z*(e1x*e2y - e1y*e2x);
  const double dsg = (detV >= 0.0) ? 1.0 : -1.0;

  double u0x = h00*e0x + h01*e0y + h02*e0z;
  double u0y = h10*e0x + h11*e0y + h12*e0z;
  double u0z = h20*e0x + h21*e0y + h22*e0z;
  double n0 = sqrt(u0x*u0x + u0y*u0y + u0z*u0z);
  if (!(n0 > 1e-150)) {
    R[0]=1.0; R[1]=0.0; R[2]=0.0; R[3]=0.0; R[4]=1.0; R[5]=0.0;
    R[6]=0.0; R[7]=0.0; R[8]=1.0;
    T[0]=c2x-c1x; T[1]=c2y-c1y; T[2]=c2z-c1z;
    return;
  }
  u0x /= n0; u0y /= n0; u0z /= n0;
  double u1x = h00*e1x + h01*e1y + h02*e1z;
  double u1y = h10*e1x + h11*e1y + h12*e1z;
  double u1z = h20*e1x + h21*e1y + h22*e1z;
  const double d10 = u1x*u0x + u1y*u0y + u1z*u0z;
  u1x -= d10*u0x; u1y -= d10*u0y; u1z -= d10*u0z;
  double n1 = sqrt(u1x*u1x + u1y*u1y + u1z*u1z);
  if (!(n1 > 1e-150)) {
    R[0]=1.0; R[1]=0.0; R[2]=0.0; R[3]=0.0; R[4]=1.0; R[5]=0.0;
    R[6]=0.0; R[7]=0.0; R[8]=1.0;
    T[0]=c2x-c1x; T[1]=c2y-c1y; T[2]=c2z-c1z;
    return;
  }
  u1x /= n1; u1y /= n1; u1z /= n1;
  const double u2x = u0y*u1z - u0z*u1y;
  const double u2y = u0z*u1x - u0x*u1z;
  const double u2z = u0x*u1y - u0y*u1x;

  R[0] = e0x*u0x + e1x*u1x + dsg*e2x*u2x;
  R[1] = e0x*u0y + e1x*u1y + dsg*e2x*u2y;
  R[2] = e0x*u0z + e1x*u1z + dsg*e2x*u2z;
  R[3] = e0y*u0x + e1y*u1x + dsg*e2y*u2x;
  R[4] = e0y*u0y + e1y*u1y + dsg*e2y*u2y;
  R[5] = e0y*u0z + e1y*u1z + dsg*e2y*u2z;
  R[6] = e0z*u0x + e1z*u1x + dsg*e2z*u2x;
  R[7] = e0z*u0y + e1z*u1y + dsg*e2z*u2y;
  R[8] = e0z*u0z + e1z*u1z + dsg*e2z*u2z;
  T[0] = c2x - (R[0]*c1x + R[1]*c1y + R[2]*c1z);
  T[1] = c2y - (R[3]*c1x + R[4]*c1y + R[5]*c1z);
  T[2] = c2z - (R[6]*c1x + R[7]*c1y + R[8]*c1z);
}

// ---------------------------------------------------------------------------
// One FUSED ICP iteration per dispatch (22 slots). R22 exact revert (best
// measured: 480 us). 512 thr / 8 waves; wave owns 4 queries end-to-end;
// 2-chunk direct global->LDS staging; wave-local u64 butterfly argmin;
// 16-set contention tree tail with solver in the root-last block.
// ---------------------------------------------------------------------------
__global__ __launch_bounds__(BSIZE) void icp_step(const float* __restrict__ p1,
                                                  const float4* __restrict__ p2aug,
                                                  IcpCtl* __restrict__ ctl,
                                                  double* __restrict__ acc,
                                                  unsigned* __restrict__ gtick,
                                                  unsigned* __restrict__ root,
                                                  float* __restrict__ out) {
  if (ctl->done) return;                    // uniform across grid
  __shared__ float4 cand[CH];               // 64 KiB
  __shared__ unsigned long long pkbuf[8][5];// wave x 4 queries (+1 pad)
  __shared__ float4 qlds[32];
  __shared__ double pairbuf[32][17];        // +1 pad
  __shared__ double setbuf[16][17];         // solver: per-set sums (+1 pad)
  __shared__ double totbuf[16];
  __shared__ int solverFlag;

  const int tid  = threadIdx.x;
  const int lane = tid & 63;
  const int w    = tid >> 6;                // wave 0..7
  const int bid  = blockIdx.x;

  if (tid == 0) solverFlag = 0;

  const double R0 = ctl->Rc[0], R1 = ctl->Rc[1], R2 = ctl->Rc[2];
  const double R3 = ctl->Rc[3], R4 = ctl->Rc[4], R5 = ctl->Rc[5];
  const double R6 = ctl->Rc[6], R7 = ctl->Rc[7], R8 = ctl->Rc[8];
  const double T0 = ctl->tc[0], T1 = ctl->tc[1], T2 = ctl->tc[2];

  // ---- wave w owns queries qb..qb+3 end-to-end (uniform across lanes) ----
  const int qb = (bid << 5) + (w << 2);
  float axv[QPW], ayv[QPW], azv[QPW], best[QPW];
  int bidx[QPW];
  #pragma unroll
  for (int j = 0; j < QPW; ++j) {
    const int q = qb + j;
    const double X = (double)p1[3*q], Y = (double)p1[3*q+1], Z = (double)p1[3*q+2];
    const float qx = (float)(R0*X + R1*Y + R2*Z + T0);  // fp32-rounded (ref pc)
    const float qy = (float)(R3*X + R4*Y + R5*Z + T1);
    const float qz = (float)(R6*X + R7*Y + R8*Z + T2);
    axv[j] = -2.f*qx; ayv[j] = -2.f*qy; azv[j] = -2.f*qz;
    best[j] = __builtin_inff(); bidx[j] = 0;
    if (lane == 0) qlds[(w << 2) + j] = make_float4(qx, qy, qz, 0.f);
  }

  // ---- scan all candidates: 2 chunks of 4096, direct global->LDS ----
  for (int cb = 0; cb < NCH; ++cb) {
    const int cbase = cb << 12;
    #pragma unroll
    for (int kk = 0; kk < 8; ++kk)
      cand[(kk << 9) + tid] = p2aug[cbase + (kk << 9) + tid];
    __syncthreads();
    #pragma unroll 4
    for (int kk = 0; kk < 64; ++kk) {
      const int cidx = cbase + (kk << 6) + lane;
      float4 c = cand[(kk << 6) + lane];    // ds_read_b128, conflict-free
      #pragma unroll
      for (int j = 0; j < QPW; ++j) {
        float d = fmaf(axv[j], c.x, fmaf(ayv[j], c.y, fmaf(azv[j], c.z, c.w)));
        if (d < best[j]) { best[j] = d; bidx[j] = cidx; }
      }
    }
    __syncthreads();
  }

  // ---- wave-local FINAL argmin: packed u64 butterfly (jnp tie order) ----
  unsigned long long pk[QPW];
  #pragma unroll
  for (int j = 0; j < QPW; ++j) {
    unsigned u = __float_as_uint(best[j]);
    u ^= (unsigned)((int)u >> 31) | 0x80000000u;   // monotone float->uint
    pk[j] = ((unsigned long long)u << 32) | (unsigned)bidx[j];
  }
  #pragma unroll
  for (int j = 0; j < QPW; ++j) {
    #pragma unroll
    for (int o = 1; o < 64; o <<= 1) {
      unsigned long long other = __shfl_xor(pk[j], o, 64);
      pk[j] = (other < pk[j]) ? other : pk[j];
    }
  }
  if (lane == 0) {
    #pragma unroll
    for (int j = 0; j < QPW; ++j) pkbuf[w][j] = pk[j];
  }
  __syncthreads();

  // ---- pair sums: tid<32 handles one query (LDS-indexed, static) ----
  if (tid < 32) {
    const unsigned long long m = pkbuf[tid >> 2][tid & 3];
    const unsigned idx = (unsigned)(m & 0xffffffffull);
    const float4 q4 = qlds[tid];
    const float4 b4 = p2aug[idx];           // L2-resident gather
    const double ax = q4.x, ay = q4.y, az = q4.z;
    const double bx = b4.x, by = b4.y, bz = b4.z;
    const double d2 = (ax*ax + ay*ay + az*az) + (bx*bx + by*by + bz*bz)
                    - 2.0*(ax*bx + ay*by + az*bz);
    pairbuf[tid][0]  = sqrt(fmax(d2, 1e-12));
    pairbuf[tid][1]  = ax;    pairbuf[tid][2]  = ay;    pairbuf[tid][3]  = az;
    pairbuf[tid][4]  = bx;    pairbuf[tid][5]  = by;    pairbuf[tid][6]  = bz;
    pairbuf[tid][7]  = ax*bx; pairbuf[tid][8]  = ax*by; pairbuf[tid][9]  = ax*bz;
    pairbuf[tid][10] = ay*bx; pairbuf[tid][11] = ay*by; pairbuf[tid][12] = ay*bz;
    pairbuf[tid][13] = az*bx; pairbuf[tid][14] = az*by; pairbuf[tid][15] = az*bz;
  }
  __syncthreads();

  // ---- 16 col sums -> atomicAdd into set (bid&15): <=16-way contention ----
  if (tid < 16) {
    double ssum = 0.0;
    #pragma unroll
    for (int i = 0; i < 32; ++i) ssum += pairbuf[i][tid];
    atomicAdd(acc + ((bid & 15) << 4) + tid, ssum);
  }
  // ticket tree (wave 0 issued the adds; vmcnt orders adds before tickets)
  if (tid == 0) {
    asm volatile("s_waitcnt vmcnt(0)" ::: "memory");
    const int gi = bid & 15;
    unsigned og = atomicAdd(gtick + (gi << 4), 1u);     // 16-way
    if (og == 15u) {                                    // last of group
      unsigned orr = atomicAdd(root, 1u);               // 16-way
      if (orr == 15u) solverFlag = 1;                   // last overall
    }
  }
  __syncthreads();
  if (!solverFlag) return;

  // ================= solver path (root-last block only) =================
  double val = 0.0;
  if (tid < 256) val = atomicAdd(acc + tid, 0.0);   // RMW-read 32 lines
  if (tid < 256) setbuf[tid >> 4][tid & 15] = val;
  __syncthreads();
  if (tid < 16) {
    double t2 = 0.0;
    #pragma unroll
    for (int i = 0; i < 16; ++i) t2 += setbuf[i][tid];
    totbuf[tid] = t2;
  }
  __syncthreads();

  if (tid == 0) {
    double sm[16];
    #pragma unroll
    for (int i = 0; i < 16; ++i) sm[i] = totbuf[i];
    double R[9], T[3];
    kabsch_solve(sm, R, T);
    // compose: pc_new = R*(Rc*p1 + tc) + T = (R*Rc)*p1 + (R*tc + T)
    double Rc[9] = {R0,R1,R2,R3,R4,R5,R6,R7,R8};
    double tc[3] = {T0,T1,T2};
    double Rn[9], tn[3];
    #pragma unroll
    for (int i = 0; i < 3; ++i) {
      #pragma unroll
      for (int j = 0; j < 3; ++j)
        Rn[3*i+j] = R[3*i+0]*Rc[0+j] + R[3*i+1]*Rc[3+j] + R[3*i+2]*Rc[6+j];
      tn[i] = R[3*i+0]*tc[0] + R[3*i+1]*tc[1] + R[3*i+2]*tc[2] + T[i];
    }
    #pragma unroll
    for (int i = 0; i < 9; ++i) ctl->Rc[i] = Rn[i];
    #pragma unroll
    for (int i = 0; i < 3; ++i) ctl->tc[i] = tn[i];
    const double errnew = sm[0];            // B == 1
    ctl->done = (fabs(ctl->err - errnew) < ICP_TOL) ? 1 : 0;
    ctl->err  = errnew;
    // out = [Rc | tc] 3x4 (kabsch(p1, Rc*p1+tc) == (Rc,tc) exactly).
    #pragma unroll
    for (int i = 0; i < 3; ++i) {
      out[4*i + 0] = (float)Rn[3*i + 0];
      out[4*i + 1] = (float)Rn[3*i + 1];
      out[4*i + 2] = (float)Rn[3*i + 2];
      out[4*i + 3] = (float)tn[i];
    }
    *root = 0u;                             // reset root ticket
  }
  // reset acc + group tickets (plain stores; boundary release publishes)
  if (tid < 256) acc[tid] = 0.0;
  if (tid < 16) gtick[tid << 4] = 0u;
}

// ---------------------------------------------------------------------------
extern "C" void kernel_launch(void* const* d_in, const int* in_sizes, int n_in,
                              void* d_out, int out_size, void* d_ws, size_t ws_size,
                              hipStream_t stream) {
  const float* p1 = (const float*)d_in[0];
  const float* p2 = (const float*)d_in[1];
  float* out = (float*)d_out;

  char* ws = (char*)d_ws;
  float4* p2aug  = (float4*)ws;                        // 128 KiB
  IcpCtl* ctl    = (IcpCtl*)(ws + 128*1024);           // ~112 B
  double* acc    = (double*)(ws + 132*1024);           // 2 KiB (16 sets x 16)
  unsigned* gtick = (unsigned*)(ws + 136*1024);        // 16 tickets, 64B apart
  unsigned* root  = (unsigned*)(ws + 140*1024);        // 1 line

  icp_prep<<<N_PTS/256, 256, 0, stream>>>(p2, p2aug, ctl, acc, gtick, root);
  for (int it = 0; it < ICP_STEPS; ++it)
    icp_step<<<NBLK, BSIZE, 0, stream>>>(p1, p2aug, ctl, acc, gtick, root, out);
}